// Round 4
// baseline (398.700 us; speedup 1.0000x reference)
//
#include <hip/hip_runtime.h>
#include <hip/hip_bf16.h>

#define BB 64
#define TT 512
#define EE 768
#define CC 20
#define MID 256
#define NB 4  // chains (batch elements) multiplexed per wave

typedef __attribute__((ext_vector_type(8))) short bf16x8;
typedef __attribute__((ext_vector_type(4))) float f32x4;

__device__ __forceinline__ float rlane(float x, int l) {
  return __int_as_float(__builtin_amdgcn_readlane(__float_as_int(x), l));
}
__device__ __forceinline__ short f2bf(float x) {
  union { __hip_bfloat16 h; short s; } u;
  u.h = __float2bfloat16(x);
  return u.s;
}
__device__ __forceinline__ bf16x8 pack8(float4 a, float4 b) {
  bf16x8 r;
  r[0] = f2bf(a.x); r[1] = f2bf(a.y); r[2] = f2bf(a.z); r[3] = f2bf(a.w);
  r[4] = f2bf(b.x); r[5] = f2bf(b.y); r[6] = f2bf(b.z); r[7] = f2bf(b.w);
  return r;
}

// ---------------- pre-pack fc_w into B-fragment layout (bf16); also zero loss slot
__global__ __launch_bounds__(256) void packw_kernel(const float* __restrict__ fc_w,
                                                    short* __restrict__ wfrag,
                                                    float* __restrict__ outp) {
  if (blockIdx.x == 0 && threadIdx.x == 0) outp[0] = 0.f;  // finish accumulates here
  int t = blockIdx.x * 256 + threadIdx.x;  // 0 .. 2*24*64-1
  int lane = t & 63;
  int kc = (t >> 6) % 24;
  int tile = t / (24 * 64);
  int n = tile * 16 + (lane & 15);
  if (n >= CC) n = CC - 1;
  int k0 = kc * 32 + (lane >> 4) * 8;
  const float* src = fc_w + (size_t)n * EE + k0;
  float4 x = *(const float4*)src;
  float4 y = *(const float4*)(src + 4);
  ((bf16x8*)wfrag)[t] = pack8(x, y);
}

// ---------------- emissions: 4 waves/block, 64 tokens/block, W direct from L2.
__global__ __launch_bounds__(256) void emissions_kernel(
    const float* __restrict__ hidden, const short* __restrict__ wfrag,
    const float* __restrict__ fc_b, float* __restrict__ em) {
  const int wave = threadIdx.x >> 6;
  const int lane = threadIdx.x & 63;
  const int token0 = blockIdx.x * 64 + wave * 16;
  const int m = lane & 15, q = lane >> 4;
  const float* hrow = hidden + (size_t)(token0 + m) * EE + q * 8;
  const bf16x8* wp = (const bf16x8*)wfrag;  // 48 KiB, L2-resident broadcast
  f32x4 acc0 = {0.f, 0.f, 0.f, 0.f}, acc1 = {0.f, 0.f, 0.f, 0.f};
#pragma unroll 4
  for (int kb = 0; kb < 24; ++kb) {
    float4 a0 = *(const float4*)(hrow + kb * 32);
    float4 a1 = *(const float4*)(hrow + kb * 32 + 4);
    bf16x8 Ab = pack8(a0, a1);
    bf16x8 w0 = wp[kb * 64 + lane];
    bf16x8 w1 = wp[(24 + kb) * 64 + lane];
    acc0 = __builtin_amdgcn_mfma_f32_16x16x32_bf16(Ab, w0, acc0, 0, 0, 0);
    acc1 = __builtin_amdgcn_mfma_f32_16x16x32_bf16(Ab, w1, acc1, 0, 0, 0);
  }
  const int col = lane & 15;
  const float b0v = fc_b[col];
  const bool has1 = (16 + col < CC);
  const float b1v = has1 ? fc_b[16 + col] : 0.f;
#pragma unroll
  for (int r = 0; r < 4; ++r) {
    int tok = token0 + q * 4 + r;
    em[(size_t)tok * CC + col] = acc0[r] + b0v;
    if (has1) em[(size_t)tok * CC + 16 + col] = acc1[r] + b1v;
  }
}

// ---- packed-u32 argmax vstep (VCC-free). Positive-biased inputs required.
__device__ __forceinline__ unsigned umax_(unsigned a, unsigned b) { return a > b ? a : b; }
__device__ __forceinline__ unsigned umax3_(unsigned a, unsigned b, unsigned c) {
  return umax_(umax_(a, b), c);
}
__device__ __forceinline__ void vstep(float a, const float (&tv)[CC], float& vm, int& jm) {
#define PKEY(Q) unsigned p##Q = (__float_as_uint(rlane(a, Q) + tv[Q]) & 0xFFFFFFE0u) | Q##u;
  PKEY(0) PKEY(1) PKEY(2) PKEY(3) PKEY(4) PKEY(5) PKEY(6) PKEY(7)
  PKEY(8) PKEY(9) PKEY(10) PKEY(11) PKEY(12) PKEY(13) PKEY(14)
  PKEY(15) PKEY(16) PKEY(17) PKEY(18) PKEY(19)
#undef PKEY
  unsigned m0 = umax3_(p0, p1, p2);
  unsigned m1 = umax3_(p3, p4, p5);
  unsigned m2 = umax3_(p6, p7, p8);
  unsigned m3 = umax3_(p9, p10, p11);
  unsigned m4 = umax3_(p12, p13, p14);
  unsigned m5 = umax3_(p15, p16, p17);
  unsigned n0 = umax3_(m0, m1, m2);
  unsigned n1 = umax3_(m3, m4, m5);
  unsigned n2 = umax_(p18, p19);
  unsigned r = umax3_(n0, n1, n2);
  vm = __uint_as_float(r & 0xFFFFFFE0u);
  jm = (int)(r & 31u);
}

#define XDECL(Q) float x##Q = rlane(x, Q); int y##Q = Q;
#define MRX(A_, B_) { bool k_ = (x##A_ >= x##B_); x##A_ = k_ ? x##A_ : x##B_; y##A_ = k_ ? y##A_ : y##B_; }
__device__ __forceinline__ int lane_argmax(float x) {
  XDECL(0) XDECL(1) XDECL(2) XDECL(3) XDECL(4) XDECL(5) XDECL(6) XDECL(7)
  XDECL(8) XDECL(9) XDECL(10) XDECL(11) XDECL(12) XDECL(13) XDECL(14)
  XDECL(15) XDECL(16) XDECL(17) XDECL(18) XDECL(19)
  MRX(0, 10) MRX(1, 11) MRX(2, 12) MRX(3, 13) MRX(4, 14)
  MRX(5, 15) MRX(6, 16) MRX(7, 17) MRX(8, 18) MRX(9, 19)
  MRX(0, 5) MRX(1, 6) MRX(2, 7) MRX(3, 8) MRX(4, 9)
  MRX(0, 1) MRX(2, 3)
  MRX(0, 2) MRX(0, 4)
  return y0;
}

__device__ __forceinline__ float fdot(float Es, const float (&ET)[CC]) {
  float s0 = rlane(Es, 0) * ET[0];
  float s1 = rlane(Es, 1) * ET[1];
  float s2 = rlane(Es, 2) * ET[2];
  float s3 = rlane(Es, 3) * ET[3];
  s0 = fmaf(rlane(Es, 4), ET[4], s0);
  s1 = fmaf(rlane(Es, 5), ET[5], s1);
  s2 = fmaf(rlane(Es, 6), ET[6], s2);
  s3 = fmaf(rlane(Es, 7), ET[7], s3);
  s0 = fmaf(rlane(Es, 8), ET[8], s0);
  s1 = fmaf(rlane(Es, 9), ET[9], s1);
  s2 = fmaf(rlane(Es, 10), ET[10], s2);
  s3 = fmaf(rlane(Es, 11), ET[11], s3);
  s0 = fmaf(rlane(Es, 12), ET[12], s0);
  s1 = fmaf(rlane(Es, 13), ET[13], s1);
  s2 = fmaf(rlane(Es, 14), ET[14], s2);
  s3 = fmaf(rlane(Es, 15), ET[15], s3);
  s0 = fmaf(rlane(Es, 16), ET[16], s0);
  s1 = fmaf(rlane(Es, 17), ET[17], s1);
  s2 = fmaf(rlane(Es, 18), ET[18], s2);
  s3 = fmaf(rlane(Es, 19), ET[19], s3);
  return (s0 + s1) + (s2 + s3);
}

#define RENORM(Xs, iev)                                        \
  {                                                            \
    float p_ = rlane(Xs, 0);                                   \
    int e_ = ((__float_as_int(p_) >> 23) & 255) - 127;         \
    Xs *= __int_as_float((127 - e_) << 23);                    \
    iev += e_;                                                 \
  }

// ---------------- CRF halves, NB=4 chains multiplexed per wave.
// Grid: 4 quads x (BB/NB) groups = 64 single-wave blocks. em/mask read direct
// from global (L2-resident, 80B broadcast rows), prefetched 1 step ahead.
// quad: 0=fwd-fore 1=fwd-back 2=vit-fore 3=vit-back
__global__ __launch_bounds__(64) void crf_half_kernel(
    const float* __restrict__ em, const int* __restrict__ mask,
    const float* __restrict__ st, const float* __restrict__ en,
    const float* __restrict__ tr,
    float* __restrict__ amw, float* __restrict__ bmw,
    float* __restrict__ avw, float* __restrict__ bvw,
    unsigned char* __restrict__ bpws, unsigned char* __restrict__ fpws) {
  const int tid = threadIdx.x;
  const int quad = blockIdx.x >> 4;
  const int b0 = (blockIdx.x & 15) * NB;
  const int cc = tid < CC ? tid : CC - 1;
  const float K = 1.44269504088896340736f;
  const float BIAS = 64.0f;
  const float* eb = em + (size_t)b0 * TT * CC;   // chain i at +i*TT*CC
  const int* mb = mask + b0 * TT;                // chain i at +i*TT

  if (quad == 0) {
    // ===== forward alpha, t=1..MID, linear domain =====
    float ET[CC];
#pragma unroll
    for (int q = 0; q < CC; ++q) ET[q] = __builtin_amdgcn_exp2f(tr[q * CC + cc] * K);
    float Es[NB], off[NB], eec[NB];
    int ie[NB], mcur[NB];
#pragma unroll
    for (int i = 0; i < NB; ++i) {
      float r = st[cc] + eb[i * TT * CC + cc];
      float bv = rlane(r, 0);
      Es[i] = __builtin_amdgcn_exp2f((r - bv) * K);
      off[i] = bv * K;
      ie[i] = 0;
      eec[i] = __builtin_amdgcn_exp2f(eb[i * TT * CC + CC + cc] * K);
      mcur[i] = mb[i * TT + 1];
    }
    for (int t = 1; t <= MID; ++t) {
      int tn = (t < MID) ? t + 1 : t;
      float emn[NB]; int mn[NB];
#pragma unroll
      for (int i = 0; i < NB; ++i) {
        emn[i] = eb[i * TT * CC + tn * CC + cc];
        mn[i] = mb[i * TT + tn];
      }
#pragma unroll
      for (int i = 0; i < NB; ++i) {
        float s = fdot(Es[i], ET) * eec[i];
        Es[i] = mcur[i] ? s : Es[i];
      }
      if ((t & 7) == 0) {
#pragma unroll
        for (int i = 0; i < NB; ++i) RENORM(Es[i], ie[i])
      }
#pragma unroll
      for (int i = 0; i < NB; ++i) {
        eec[i] = __builtin_amdgcn_exp2f(emn[i] * K);
        mcur[i] = mn[i];
      }
    }
    if (tid < CC) {
#pragma unroll
      for (int i = 0; i < NB; ++i)
        amw[(b0 + i) * CC + tid] = off[i] + (float)ie[i] + __builtin_amdgcn_logf(Es[i]);
    }
  } else if (quad == 1) {
    // ===== backward beta, t=T-2..MID, linear domain, mask-reset to en =====
    float ETr[CC];
#pragma unroll
    for (int q = 0; q < CC; ++q) ETr[q] = __builtin_amdgcn_exp2f(tr[cc * CC + q] * K);
    const float ENc = __builtin_amdgcn_exp2f(en[cc] * K);
    float Bs[NB], ee1[NB];
    int ie[NB], m1[NB];
#pragma unroll
    for (int i = 0; i < NB; ++i) {
      Bs[i] = ENc;
      ie[i] = 0;
      ee1[i] = __builtin_amdgcn_exp2f(eb[i * TT * CC + (TT - 1) * CC + cc] * K);
      m1[i] = mb[i * TT + TT - 1];
    }
    for (int t = TT - 2; t >= MID; --t) {
      float emn[NB]; int mn[NB];
#pragma unroll
      for (int i = 0; i < NB; ++i) {
        emn[i] = eb[i * TT * CC + t * CC + cc];
        mn[i] = mb[i * TT + t];
      }
#pragma unroll
      for (int i = 0; i < NB; ++i) {
        float G = Bs[i] * ee1[i];
        float s = fdot(G, ETr);
        Bs[i] = m1[i] ? s : ENc;
        ie[i] = m1[i] ? ie[i] : 0;
      }
      if ((t & 7) == 0) {
#pragma unroll
        for (int i = 0; i < NB; ++i) RENORM(Bs[i], ie[i])
      }
#pragma unroll
      for (int i = 0; i < NB; ++i) {
        ee1[i] = __builtin_amdgcn_exp2f(emn[i] * K);
        m1[i] = mn[i];
      }
    }
    if (tid < CC) {
#pragma unroll
      for (int i = 0; i < NB; ++i)
        bmw[(b0 + i) * CC + tid] = (float)ie[i] + __builtin_amdgcn_logf(Bs[i]);
    }
  } else if (quad == 2) {
    // ===== viterbi fore, t=1..MID, biased-positive state, packed-u32 argmax =====
    float tv[CC];
#pragma unroll
    for (int q = 0; q < CC; ++q) tv[q] = tr[q * CC + cc];
    float a[NB], emc[NB];
    int mcur[NB];
#pragma unroll
    for (int i = 0; i < NB; ++i) {
      a[i] = st[cc] + eb[i * TT * CC + cc] + BIAS;
      emc[i] = eb[i * TT * CC + CC + cc];
      mcur[i] = mb[i * TT + 1];
    }
    for (int t = 1; t <= MID; ++t) {
      int tn = (t < MID) ? t + 1 : t;
      float emn[NB]; int mn[NB];
#pragma unroll
      for (int i = 0; i < NB; ++i) {
        emn[i] = eb[i * TT * CC + tn * CC + cc];
        mn[i] = mb[i * TT + tn];
      }
#pragma unroll
      for (int i = 0; i < NB; ++i) {
        float vm; int jm;
        vstep(a[i], tv, vm, jm);
        if (tid < CC) bpws[(size_t)(b0 + i) * MID * CC + (t - 1) * CC + tid] = (unsigned char)jm;
        float au = vm + emc[i];
        a[i] = mcur[i] ? au : a[i];
      }
      if ((t & 7) == 0) {
#pragma unroll
        for (int i = 0; i < NB; ++i) a[i] += (BIAS - rlane(a[i], 0));
      }
#pragma unroll
      for (int i = 0; i < NB; ++i) { emc[i] = emn[i]; mcur[i] = mn[i]; }
    }
    if (tid < CC) {
#pragma unroll
      for (int i = 0; i < NB; ++i) avw[(b0 + i) * CC + tid] = a[i];
    }
  } else {
    // ===== viterbi back, t=T-2..MID, biased-positive state, packed-u32 argmax =====
    float tv[CC];
#pragma unroll
    for (int q = 0; q < CC; ++q) tv[q] = tr[cc * CC + q];
    const float ENv = en[cc] + BIAS;
    float Vb[NB], em1[NB];
    int m1[NB];
#pragma unroll
    for (int i = 0; i < NB; ++i) {
      Vb[i] = ENv;
      em1[i] = eb[i * TT * CC + (TT - 1) * CC + cc];
      m1[i] = mb[i * TT + TT - 1];
    }
    for (int t = TT - 2; t >= MID; --t) {
      float emn[NB]; int mn[NB];
#pragma unroll
      for (int i = 0; i < NB; ++i) {
        emn[i] = eb[i * TT * CC + t * CC + cc];
        mn[i] = mb[i * TT + t];
      }
#pragma unroll
      for (int i = 0; i < NB; ++i) {
        float av = Vb[i] + em1[i];
        float vm; int jm;
        vstep(av, tv, vm, jm);
        if (tid < CC) fpws[(size_t)(b0 + i) * MID * CC + (t - MID) * CC + tid] = (unsigned char)jm;
        Vb[i] = m1[i] ? vm : ENv;
      }
      if ((t & 7) == 0) {
#pragma unroll
        for (int i = 0; i < NB; ++i) Vb[i] += (BIAS - rlane(Vb[i], 0));
      }
#pragma unroll
      for (int i = 0; i < NB; ++i) { em1[i] = emn[i]; m1[i] = mn[i]; }
    }
    if (tid < CC) {
#pragma unroll
      for (int i = 0; i < NB; ++i) bvw[(b0 + i) * CC + tid] = Vb[i];
    }
  }
}

// ---------------- finish: join halves, backtrace both ways, numerator, llh, loss
__global__ __launch_bounds__(64) void finish_kernel(
    const float* __restrict__ em, const int* __restrict__ mask,
    const int* __restrict__ labels, const float* __restrict__ st,
    const float* __restrict__ en, const float* __restrict__ tr,
    const float* __restrict__ amw, const float* __restrict__ bmw,
    const float* __restrict__ avw, const float* __restrict__ bvw,
    const unsigned char* __restrict__ bpws, const unsigned char* __restrict__ fpws,
    float* __restrict__ out) {
  __shared__ unsigned char hl[2 * MID * CC];  // 10240
  const int b = blockIdx.x;
  const int tid = threadIdx.x;
  const int cc = tid < CC ? tid : CC - 1;
  const float LN2 = 0.69314718055994530942f;
  {
    const int4* bsrc = (const int4*)(bpws + (size_t)b * MID * CC);
    const int4* fsrc = (const int4*)(fpws + (size_t)b * MID * CC);
    int4* dst = (int4*)hl;
    for (int i = tid; i < 320; i += 64) {
      dst[i] = bsrc[i];
      dst[320 + i] = fsrc[i];
    }
  }
  __syncthreads();

  // --- viterbi join + dual backtrace ---
  int cstar = lane_argmax(avw[b * CC + cc] + bvw[b * CC + cc]);
  float* ob = out + 1 + (size_t)b * TT;
  if (tid == 0) ob[MID] = (float)(cstar + 1);
  // backward: s = 255..0, tag_s = bp[s][tag_{s+1}] ; 256 = 32*8 exact
  {
    int tag = cstar;
    int s = MID - 1;
    while (s >= 7) {
      int g0 = hl[(s - 0) * CC + cc];
      int g1 = hl[(s - 1) * CC + cc];
      int g2 = hl[(s - 2) * CC + cc];
      int g3 = hl[(s - 3) * CC + cc];
      int g4 = hl[(s - 4) * CC + cc];
      int g5 = hl[(s - 5) * CC + cc];
      int g6 = hl[(s - 6) * CC + cc];
      int g7 = hl[(s - 7) * CC + cc];
      tag = __builtin_amdgcn_readlane(g0, tag); float f0 = (float)(tag + 1);
      tag = __builtin_amdgcn_readlane(g1, tag); float f1 = (float)(tag + 1);
      tag = __builtin_amdgcn_readlane(g2, tag); float f2 = (float)(tag + 1);
      tag = __builtin_amdgcn_readlane(g3, tag); float f3 = (float)(tag + 1);
      tag = __builtin_amdgcn_readlane(g4, tag); float f4 = (float)(tag + 1);
      tag = __builtin_amdgcn_readlane(g5, tag); float f5 = (float)(tag + 1);
      tag = __builtin_amdgcn_readlane(g6, tag); float f6 = (float)(tag + 1);
      tag = __builtin_amdgcn_readlane(g7, tag); float f7 = (float)(tag + 1);
      if (tid == 0) {
        ob[s - 0] = f0; ob[s - 1] = f1; ob[s - 2] = f2; ob[s - 3] = f3;
        ob[s - 4] = f4; ob[s - 5] = f5; ob[s - 6] = f6; ob[s - 7] = f7;
      }
      s -= 8;
    }
  }
  // forward: u = 0..254, tag_{t+1} = fp[u][tag_t], t = MID+u
  {
    int tag = cstar;
    int u = 0;
    while (u + 7 <= MID - 2) {
      int g0 = hl[MID * CC + (u + 0) * CC + cc];
      int g1 = hl[MID * CC + (u + 1) * CC + cc];
      int g2 = hl[MID * CC + (u + 2) * CC + cc];
      int g3 = hl[MID * CC + (u + 3) * CC + cc];
      int g4 = hl[MID * CC + (u + 4) * CC + cc];
      int g5 = hl[MID * CC + (u + 5) * CC + cc];
      int g6 = hl[MID * CC + (u + 6) * CC + cc];
      int g7 = hl[MID * CC + (u + 7) * CC + cc];
      tag = __builtin_amdgcn_readlane(g0, tag); float f0 = (float)(tag + 1);
      tag = __builtin_amdgcn_readlane(g1, tag); float f1 = (float)(tag + 1);
      tag = __builtin_amdgcn_readlane(g2, tag); float f2 = (float)(tag + 1);
      tag = __builtin_amdgcn_readlane(g3, tag); float f3 = (float)(tag + 1);
      tag = __builtin_amdgcn_readlane(g4, tag); float f4 = (float)(tag + 1);
      tag = __builtin_amdgcn_readlane(g5, tag); float f5 = (float)(tag + 1);
      tag = __builtin_amdgcn_readlane(g6, tag); float f6 = (float)(tag + 1);
      tag = __builtin_amdgcn_readlane(g7, tag); float f7 = (float)(tag + 1);
      if (tid == 0) {
        ob[MID + 1 + u + 0] = f0; ob[MID + 1 + u + 1] = f1;
        ob[MID + 1 + u + 2] = f2; ob[MID + 1 + u + 3] = f3;
        ob[MID + 1 + u + 4] = f4; ob[MID + 1 + u + 5] = f5;
        ob[MID + 1 + u + 6] = f6; ob[MID + 1 + u + 7] = f7;
      }
      u += 8;
    }
    while (u <= MID - 2) {
      int g = hl[MID * CC + u * CC + cc];
      tag = __builtin_amdgcn_readlane(g, tag);
      if (tid == 0) ob[MID + 1 + u] = (float)(tag + 1);
      ++u;
    }
  }

  // --- norm = LN2 * lse2(am + bm) ---
  float zn = amw[b * CC + cc] + bmw[b * CC + cc];
  float M = zn;
#pragma unroll
  for (int o = 32; o >= 1; o >>= 1) M = fmaxf(M, __shfl_xor(M, o));
  float sE = (tid < CC) ? __builtin_amdgcn_exp2f(zn - M) : 0.f;
#pragma unroll
  for (int o = 32; o >= 1; o >>= 1) sE += __shfl_xor(sE, o);
  float norm = LN2 * (M + __builtin_amdgcn_logf(sE));

  // --- numerator ---
  const int* lab = labels + b * TT;
  const float* emg = em + (size_t)b * TT * CC;
  float sc = 0.f;
  int msum = 0;
  for (int k = tid; k < TT; k += 64) {
    int mk = mask[b * TT + k];
    msum += mk;
    if (k >= 1) {
      int tg = lab[k], tp = lab[k - 1];
      sc += (tr[tp * CC + tg] + emg[k * CC + tg]) * (float)mk;
    }
  }
#pragma unroll
  for (int o = 32; o >= 1; o >>= 1) {
    sc += __shfl_xor(sc, o);
    msum += __shfl_xor(msum, o);
  }
  int seq_end = msum - 1;
  int t0 = lab[0], tl = lab[seq_end];
  float score = sc + st[t0] + emg[t0] + en[tl];
  // loss = mean(norm - score); out[0] pre-zeroed by packw_kernel
  if (tid == 0) atomicAdd(out, (norm - score) * (1.0f / 64.0f));
}

extern "C" void kernel_launch(void* const* d_in, const int* in_sizes, int n_in,
                              void* d_out, int out_size, void* d_ws, size_t ws_size,
                              hipStream_t stream) {
  const float* hidden = (const float*)d_in[0];
  const int* amask = (const int*)d_in[1];
  const int* labels = (const int*)d_in[2];
  const float* fc_w = (const float*)d_in[3];
  const float* fc_b = (const float*)d_in[4];
  const float* st = (const float*)d_in[5];
  const float* en = (const float*)d_in[6];
  const float* tr = (const float*)d_in[7];

  float* emws = (float*)d_ws;                          // 655360 floats
  float* llh = emws + (size_t)BB * TT * CC;            // 64 (unused, keeps layout)
  short* wfrag = (short*)(llh + 64);                   // 24576 shorts
  float* amw = (float*)(wfrag + 24576);                // 1280
  float* bmw = amw + BB * CC;
  float* avw = bmw + BB * CC;
  float* bvw = avw + BB * CC;
  unsigned char* bpws = (unsigned char*)(bvw + BB * CC);  // 327680 B (16B aligned)
  unsigned char* fpws = bpws + (size_t)BB * MID * CC;     // 327680 B
  float* out = (float*)d_out;

  packw_kernel<<<(2 * 24 * 64) / 256, 256, 0, stream>>>(fc_w, wfrag, out);
  emissions_kernel<<<(BB * TT) / 64, 256, 0, stream>>>(hidden, wfrag, fc_b, emws);
  crf_half_kernel<<<4 * (BB / NB), 64, 0, stream>>>(emws, amask, st, en, tr,
                                                    amw, bmw, avw, bvw, bpws, fpws);
  finish_kernel<<<BB, 64, 0, stream>>>(emws, amask, labels, st, en, tr,
                                       amw, bmw, avw, bvw, bpws, fpws, out);
}

// Round 5
// 243.565 us; speedup vs baseline: 1.6369x; 1.6369x over previous
//
#include <hip/hip_runtime.h>
#include <hip/hip_bf16.h>

#define BB 64
#define TT 512
#define EE 768
#define CC 20
#define MID 256

typedef __attribute__((ext_vector_type(8))) short bf16x8;
typedef __attribute__((ext_vector_type(4))) float f32x4;

__device__ __forceinline__ float rlane(float x, int l) {
  return __int_as_float(__builtin_amdgcn_readlane(__float_as_int(x), l));
}
__device__ __forceinline__ short f2bf(float x) {
  union { __hip_bfloat16 h; short s; } u;
  u.h = __float2bfloat16(x);
  return u.s;
}
__device__ __forceinline__ bf16x8 pack8(float4 a, float4 b) {
  bf16x8 r;
  r[0] = f2bf(a.x); r[1] = f2bf(a.y); r[2] = f2bf(a.z); r[3] = f2bf(a.w);
  r[4] = f2bf(b.x); r[5] = f2bf(b.y); r[6] = f2bf(b.z); r[7] = f2bf(b.w);
  return r;
}

// ---------------- pre-pack fc_w into B-fragment layout (bf16); zero loss slot
__global__ __launch_bounds__(256) void packw_kernel(const float* __restrict__ fc_w,
                                                    short* __restrict__ wfrag,
                                                    float* __restrict__ outp) {
  if (blockIdx.x == 0 && threadIdx.x == 0) outp[0] = 0.f;  // finish accumulates here
  int t = blockIdx.x * 256 + threadIdx.x;  // 0 .. 2*24*64-1
  int lane = t & 63;
  int kc = (t >> 6) % 24;
  int tile = t / (24 * 64);
  int n = tile * 16 + (lane & 15);
  if (n >= CC) n = CC - 1;
  int k0 = kc * 32 + (lane >> 4) * 8;
  const float* src = fc_w + (size_t)n * EE + k0;
  float4 x = *(const float4*)src;
  float4 y = *(const float4*)(src + 4);
  ((bf16x8*)wfrag)[t] = pack8(x, y);
}

// ---------------- emissions: 4 waves/block, 64 tokens/block, W direct from L2.
__global__ __launch_bounds__(256) void emissions_kernel(
    const float* __restrict__ hidden, const short* __restrict__ wfrag,
    const float* __restrict__ fc_b, float* __restrict__ em) {
  const int wave = threadIdx.x >> 6;
  const int lane = threadIdx.x & 63;
  const int token0 = blockIdx.x * 64 + wave * 16;
  const int m = lane & 15, q = lane >> 4;
  const float* hrow = hidden + (size_t)(token0 + m) * EE + q * 8;
  const bf16x8* wp = (const bf16x8*)wfrag;  // 48 KiB, L2-resident broadcast
  f32x4 acc0 = {0.f, 0.f, 0.f, 0.f}, acc1 = {0.f, 0.f, 0.f, 0.f};
#pragma unroll 4
  for (int kb = 0; kb < 24; ++kb) {
    float4 a0 = *(const float4*)(hrow + kb * 32);
    float4 a1 = *(const float4*)(hrow + kb * 32 + 4);
    bf16x8 Ab = pack8(a0, a1);
    bf16x8 w0 = wp[kb * 64 + lane];
    bf16x8 w1 = wp[(24 + kb) * 64 + lane];
    acc0 = __builtin_amdgcn_mfma_f32_16x16x32_bf16(Ab, w0, acc0, 0, 0, 0);
    acc1 = __builtin_amdgcn_mfma_f32_16x16x32_bf16(Ab, w1, acc1, 0, 0, 0);
  }
  const int col = lane & 15;
  const float b0v = fc_b[col];
  const bool has1 = (16 + col < CC);
  const float b1v = has1 ? fc_b[16 + col] : 0.f;
#pragma unroll
  for (int r = 0; r < 4; ++r) {
    int tok = token0 + q * 4 + r;
    em[(size_t)tok * CC + col] = acc0[r] + b0v;
    if (has1) em[(size_t)tok * CC + 16 + col] = acc1[r] + b1v;
  }
}

// ---- LDS-broadcast step kernels: state vector arrives as 5x float4 (same
// addresses for all lanes -> broadcast, 0 conflicts, no readlane in the loop).
__device__ __forceinline__ unsigned umax_(unsigned a, unsigned b) { return a > b ? a : b; }
__device__ __forceinline__ unsigned umax3_(unsigned a, unsigned b, unsigned c) {
  return umax_(umax_(a, b), c);
}
// packed-u32 argmax over 20 biased-positive values; same key/tree as R3.
__device__ __forceinline__ void vstep_lds(float4 x0, float4 x1, float4 x2, float4 x3,
                                          float4 x4, const float (&tv)[CC],
                                          float& vm, int& jm) {
  float v0 = x0.x + tv[0], v1 = x0.y + tv[1], v2 = x0.z + tv[2], v3 = x0.w + tv[3];
  float v4 = x1.x + tv[4], v5 = x1.y + tv[5], v6 = x1.z + tv[6], v7 = x1.w + tv[7];
  float v8 = x2.x + tv[8], v9 = x2.y + tv[9], v10 = x2.z + tv[10], v11 = x2.w + tv[11];
  float v12 = x3.x + tv[12], v13 = x3.y + tv[13], v14 = x3.z + tv[14], v15 = x3.w + tv[15];
  float v16 = x4.x + tv[16], v17 = x4.y + tv[17], v18 = x4.z + tv[18], v19 = x4.w + tv[19];
#define PKEY(Q) unsigned p##Q = (__float_as_uint(v##Q) & 0xFFFFFFE0u) | Q##u;
  PKEY(0) PKEY(1) PKEY(2) PKEY(3) PKEY(4) PKEY(5) PKEY(6) PKEY(7)
  PKEY(8) PKEY(9) PKEY(10) PKEY(11) PKEY(12) PKEY(13) PKEY(14)
  PKEY(15) PKEY(16) PKEY(17) PKEY(18) PKEY(19)
#undef PKEY
  unsigned m0 = umax3_(p0, p1, p2);
  unsigned m1 = umax3_(p3, p4, p5);
  unsigned m2 = umax3_(p6, p7, p8);
  unsigned m3 = umax3_(p9, p10, p11);
  unsigned m4 = umax3_(p12, p13, p14);
  unsigned m5 = umax3_(p15, p16, p17);
  unsigned n0 = umax3_(m0, m1, m2);
  unsigned n1 = umax3_(m3, m4, m5);
  unsigned n2 = umax_(p18, p19);
  unsigned r = umax3_(n0, n1, n2);
  vm = __uint_as_float(r & 0xFFFFFFE0u);
  jm = (int)(r & 31u);
}
// dot(x, ET): same accumulator grouping/order as R3's fdot -> bitwise identical.
__device__ __forceinline__ float fdot_lds(float4 x0, float4 x1, float4 x2, float4 x3,
                                          float4 x4, const float (&ET)[CC]) {
  float s0 = x0.x * ET[0];
  float s1 = x0.y * ET[1];
  float s2 = x0.z * ET[2];
  float s3 = x0.w * ET[3];
  s0 = fmaf(x1.x, ET[4], s0);
  s1 = fmaf(x1.y, ET[5], s1);
  s2 = fmaf(x1.z, ET[6], s2);
  s3 = fmaf(x1.w, ET[7], s3);
  s0 = fmaf(x2.x, ET[8], s0);
  s1 = fmaf(x2.y, ET[9], s1);
  s2 = fmaf(x2.z, ET[10], s2);
  s3 = fmaf(x2.w, ET[11], s3);
  s0 = fmaf(x3.x, ET[12], s0);
  s1 = fmaf(x3.y, ET[13], s1);
  s2 = fmaf(x3.z, ET[14], s2);
  s3 = fmaf(x3.w, ET[15], s3);
  s0 = fmaf(x4.x, ET[16], s0);
  s1 = fmaf(x4.y, ET[17], s1);
  s2 = fmaf(x4.z, ET[18], s2);
  s3 = fmaf(x4.w, ET[19], s3);
  return (s0 + s1) + (s2 + s3);
}

#define XDECL(Q) float x##Q = rlane(x, Q); int y##Q = Q;
#define MRX(A_, B_) { bool k_ = (x##A_ >= x##B_); x##A_ = k_ ? x##A_ : x##B_; y##A_ = k_ ? y##A_ : y##B_; }
__device__ __forceinline__ int lane_argmax(float x) {
  XDECL(0) XDECL(1) XDECL(2) XDECL(3) XDECL(4) XDECL(5) XDECL(6) XDECL(7)
  XDECL(8) XDECL(9) XDECL(10) XDECL(11) XDECL(12) XDECL(13) XDECL(14)
  XDECL(15) XDECL(16) XDECL(17) XDECL(18) XDECL(19)
  MRX(0, 10) MRX(1, 11) MRX(2, 12) MRX(3, 13) MRX(4, 14)
  MRX(5, 15) MRX(6, 16) MRX(7, 17) MRX(8, 18) MRX(9, 19)
  MRX(0, 5) MRX(1, 6) MRX(2, 7) MRX(3, 8) MRX(4, 9)
  MRX(0, 1) MRX(2, 3)
  MRX(0, 2) MRX(0, 4)
  return y0;
}

#define RENORM(Xs, iev)                                        \
  {                                                            \
    float p_ = rlane(Xs, 0);                                   \
    int e_ = ((__float_as_int(p_) >> 23) & 255) - 127;         \
    Xs *= __int_as_float((127 - e_) << 23);                    \
    iev += e_;                                                 \
  }

// ---------------- CRF halves. quad: 0=fwd-fore 1=fwd-back 2=vit-fore 3=vit-back
// State broadcast through LDS (ssh): lane cc writes state, all lanes read the
// 20-float vector as 5x ds_read_b128. Zero readlanes in the hot loop.
__global__ __launch_bounds__(64) void crf_half_kernel(
    const float* __restrict__ em, const int* __restrict__ mask,
    const float* __restrict__ st, const float* __restrict__ en,
    const float* __restrict__ tr,
    float* __restrict__ amw, float* __restrict__ bmw,
    float* __restrict__ avw, float* __restrict__ bvw,
    unsigned char* __restrict__ bpws, unsigned char* __restrict__ fpws) {
  __shared__ __align__(16) float emsh[(MID + 1) * CC];  // fore rows 0..256 / back rows 256..511
  __shared__ int msh[TT];
  __shared__ __align__(16) float ssh[64];  // state broadcast buffer (0..19 used)
  const int tid = threadIdx.x;
  const int quad = blockIdx.x >> 6;
  const int b = blockIdx.x & (BB - 1);
  const int back = quad & 1;
  const int cc = tid < CC ? tid : CC - 1;
  const float K = 1.44269504088896340736f;
  const float BIAS = 64.0f;
  const float4* sv = (const float4*)ssh;

  {
    const float* base = em + (size_t)b * TT * CC + (back ? MID * CC : 0);
    int nf4 = back ? (MID * CC / 4) : ((MID + 1) * CC / 4);  // 1280 or 1285
    const float4* src = (const float4*)base;
    float4* dst = (float4*)emsh;
    for (int i = tid; i < nf4; i += 64) dst[i] = src[i];
    for (int i = tid; i < TT; i += 64) msh[i] = mask[b * TT + i];
  }
  __syncthreads();

  if (quad == 0) {
    // ===== forward alpha, t=1..MID, linear domain =====
    float ET[CC];
#pragma unroll
    for (int q = 0; q < CC; ++q) ET[q] = __builtin_amdgcn_exp2f(tr[q * CC + cc] * K);
    float r = st[cc] + emsh[cc];
    float base0 = rlane(r, 0);
    float Es = __builtin_amdgcn_exp2f((r - base0) * K);
    float off = base0 * K;
    int ie = 0;
    ssh[tid] = Es;
    float eec = __builtin_amdgcn_exp2f(emsh[CC + cc] * K);
    int mcur = msh[1];
    for (int t = 1; t <= MID; ++t) {
      float4 x0 = sv[0], x1 = sv[1], x2 = sv[2], x3 = sv[3], x4 = sv[4];
      int tn = (t < MID) ? t + 1 : t;
      float emn = emsh[tn * CC + cc];
      int mn = msh[tn];
      float s = fdot_lds(x0, x1, x2, x3, x4, ET) * eec;
      Es = mcur ? s : Es;
      if ((t & 7) == 0) RENORM(Es, ie)
      ssh[tid] = Es;
      eec = __builtin_amdgcn_exp2f(emn * K);
      mcur = mn;
    }
    if (tid < CC) amw[b * CC + tid] = off + (float)ie + __builtin_amdgcn_logf(Es);
  } else if (quad == 1) {
    // ===== backward beta, t=T-2..MID, linear domain, mask-reset to en =====
    float ETr[CC];
#pragma unroll
    for (int q = 0; q < CC; ++q) ETr[q] = __builtin_amdgcn_exp2f(tr[cc * CC + q] * K);
    const float ENc = __builtin_amdgcn_exp2f(en[cc] * K);
    float Bs = ENc;
    int ie = 0;
    float ee1 = __builtin_amdgcn_exp2f(emsh[(TT - 1 - MID) * CC + cc] * K);  // exp(em_511)
    int m1 = msh[TT - 1];
    ssh[tid] = Bs * ee1;  // G for first iteration
    for (int t = TT - 2; t >= MID; --t) {
      float4 x0 = sv[0], x1 = sv[1], x2 = sv[2], x3 = sv[3], x4 = sv[4];
      float emn = emsh[(t - MID) * CC + cc];  // em_t
      int mn = msh[t];
      float s = fdot_lds(x0, x1, x2, x3, x4, ETr);
      Bs = m1 ? s : ENc;
      ie = m1 ? ie : 0;
      if ((t & 7) == 0) RENORM(Bs, ie)
      float een = __builtin_amdgcn_exp2f(emn * K);
      ssh[tid] = Bs * een;  // G for next iteration
      m1 = mn;
    }
    if (tid < CC) bmw[b * CC + tid] = (float)ie + __builtin_amdgcn_logf(Bs);
  } else if (quad == 2) {
    // ===== viterbi fore, t=1..MID, biased-positive state =====
    float tv[CC];
#pragma unroll
    for (int q = 0; q < CC; ++q) tv[q] = tr[q * CC + cc];
    float a = st[cc] + emsh[cc] + BIAS;
    ssh[tid] = a;
    float emc = emsh[CC + cc];
    int mcur = msh[1];
    unsigned char* bp = bpws + (size_t)b * MID * CC;
    for (int t = 1; t <= MID; ++t) {
      float4 x0 = sv[0], x1 = sv[1], x2 = sv[2], x3 = sv[3], x4 = sv[4];
      int tn = (t < MID) ? t + 1 : t;
      float emn = emsh[tn * CC + cc];
      int mn = msh[tn];
      float vm;
      int jm;
      vstep_lds(x0, x1, x2, x3, x4, tv, vm, jm);
      if (tid < CC) bp[(t - 1) * CC + tid] = (unsigned char)jm;
      float au = vm + emc;
      a = mcur ? au : a;
      if ((t & 7) == 0) a += (BIAS - rlane(a, 0));  // uniform shift: argmax-invariant
      ssh[tid] = a;
      emc = emn;
      mcur = mn;
    }
    if (tid < CC) avw[b * CC + tid] = a;
  } else {
    // ===== viterbi back, t=T-2..MID, biased-positive state =====
    float tv[CC];
#pragma unroll
    for (int q = 0; q < CC; ++q) tv[q] = tr[cc * CC + q];  // row of tr
    const float ENv = en[cc] + BIAS;
    float Vb = ENv;
    float em1 = emsh[(TT - 1 - MID) * CC + cc];
    int m1 = msh[TT - 1];
    ssh[tid] = Vb + em1;  // av for first iteration
    unsigned char* fp = fpws + (size_t)b * MID * CC;
    for (int t = TT - 2; t >= MID; --t) {
      float4 x0 = sv[0], x1 = sv[1], x2 = sv[2], x3 = sv[3], x4 = sv[4];
      float emn = emsh[(t - MID) * CC + cc];
      int mn = msh[t];
      float vm;
      int jm;
      vstep_lds(x0, x1, x2, x3, x4, tv, vm, jm);
      if (tid < CC) fp[(t - MID) * CC + tid] = (unsigned char)jm;
      Vb = m1 ? vm : ENv;
      if ((t & 7) == 0) Vb += (BIAS - rlane(Vb, 0));  // uniform shift: argmax-invariant
      ssh[tid] = Vb + emn;  // av for next iteration
      m1 = mn;
    }
    if (tid < CC) bvw[b * CC + tid] = Vb;
  }
}

// ---------------- finish: join halves, backtrace both ways, numerator, llh, loss
__global__ __launch_bounds__(64) void finish_kernel(
    const float* __restrict__ em, const int* __restrict__ mask,
    const int* __restrict__ labels, const float* __restrict__ st,
    const float* __restrict__ en, const float* __restrict__ tr,
    const float* __restrict__ amw, const float* __restrict__ bmw,
    const float* __restrict__ avw, const float* __restrict__ bvw,
    const unsigned char* __restrict__ bpws, const unsigned char* __restrict__ fpws,
    float* __restrict__ out) {
  __shared__ unsigned char hl[2 * MID * CC];  // 10240
  const int b = blockIdx.x;
  const int tid = threadIdx.x;
  const int cc = tid < CC ? tid : CC - 1;
  const float LN2 = 0.69314718055994530942f;
  {
    const int4* bsrc = (const int4*)(bpws + (size_t)b * MID * CC);
    const int4* fsrc = (const int4*)(fpws + (size_t)b * MID * CC);
    int4* dst = (int4*)hl;
    for (int i = tid; i < 320; i += 64) {
      dst[i] = bsrc[i];
      dst[320 + i] = fsrc[i];
    }
  }
  __syncthreads();

  // --- viterbi join + dual backtrace ---
  int cstar = lane_argmax(avw[b * CC + cc] + bvw[b * CC + cc]);
  float* ob = out + 1 + (size_t)b * TT;
  if (tid == 0) ob[MID] = (float)(cstar + 1);
  // backward: s = 255..0, tag_s = bp[s][tag_{s+1}] ; 256 = 32*8 exact
  {
    int tag = cstar;
    int s = MID - 1;
    while (s >= 7) {
      int g0 = hl[(s - 0) * CC + cc];
      int g1 = hl[(s - 1) * CC + cc];
      int g2 = hl[(s - 2) * CC + cc];
      int g3 = hl[(s - 3) * CC + cc];
      int g4 = hl[(s - 4) * CC + cc];
      int g5 = hl[(s - 5) * CC + cc];
      int g6 = hl[(s - 6) * CC + cc];
      int g7 = hl[(s - 7) * CC + cc];
      tag = __builtin_amdgcn_readlane(g0, tag); float f0 = (float)(tag + 1);
      tag = __builtin_amdgcn_readlane(g1, tag); float f1 = (float)(tag + 1);
      tag = __builtin_amdgcn_readlane(g2, tag); float f2 = (float)(tag + 1);
      tag = __builtin_amdgcn_readlane(g3, tag); float f3 = (float)(tag + 1);
      tag = __builtin_amdgcn_readlane(g4, tag); float f4 = (float)(tag + 1);
      tag = __builtin_amdgcn_readlane(g5, tag); float f5 = (float)(tag + 1);
      tag = __builtin_amdgcn_readlane(g6, tag); float f6 = (float)(tag + 1);
      tag = __builtin_amdgcn_readlane(g7, tag); float f7 = (float)(tag + 1);
      if (tid == 0) {
        ob[s - 0] = f0; ob[s - 1] = f1; ob[s - 2] = f2; ob[s - 3] = f3;
        ob[s - 4] = f4; ob[s - 5] = f5; ob[s - 6] = f6; ob[s - 7] = f7;
      }
      s -= 8;
    }
  }
  // forward: u = 0..254, tag_{t+1} = fp[u][tag_t], t = MID+u
  {
    int tag = cstar;
    int u = 0;
    while (u + 7 <= MID - 2) {
      int g0 = hl[MID * CC + (u + 0) * CC + cc];
      int g1 = hl[MID * CC + (u + 1) * CC + cc];
      int g2 = hl[MID * CC + (u + 2) * CC + cc];
      int g3 = hl[MID * CC + (u + 3) * CC + cc];
      int g4 = hl[MID * CC + (u + 4) * CC + cc];
      int g5 = hl[MID * CC + (u + 5) * CC + cc];
      int g6 = hl[MID * CC + (u + 6) * CC + cc];
      int g7 = hl[MID * CC + (u + 7) * CC + cc];
      tag = __builtin_amdgcn_readlane(g0, tag); float f0 = (float)(tag + 1);
      tag = __builtin_amdgcn_readlane(g1, tag); float f1 = (float)(tag + 1);
      tag = __builtin_amdgcn_readlane(g2, tag); float f2 = (float)(tag + 1);
      tag = __builtin_amdgcn_readlane(g3, tag); float f3 = (float)(tag + 1);
      tag = __builtin_amdgcn_readlane(g4, tag); float f4 = (float)(tag + 1);
      tag = __builtin_amdgcn_readlane(g5, tag); float f5 = (float)(tag + 1);
      tag = __builtin_amdgcn_readlane(g6, tag); float f6 = (float)(tag + 1);
      tag = __builtin_amdgcn_readlane(g7, tag); float f7 = (float)(tag + 1);
      if (tid == 0) {
        ob[MID + 1 + u + 0] = f0; ob[MID + 1 + u + 1] = f1;
        ob[MID + 1 + u + 2] = f2; ob[MID + 1 + u + 3] = f3;
        ob[MID + 1 + u + 4] = f4; ob[MID + 1 + u + 5] = f5;
        ob[MID + 1 + u + 6] = f6; ob[MID + 1 + u + 7] = f7;
      }
      u += 8;
    }
    while (u <= MID - 2) {
      int g = hl[MID * CC + u * CC + cc];
      tag = __builtin_amdgcn_readlane(g, tag);
      if (tid == 0) ob[MID + 1 + u] = (float)(tag + 1);
      ++u;
    }
  }

  // --- norm = LN2 * lse2(am + bm) ---
  float zn = amw[b * CC + cc] + bmw[b * CC + cc];
  float M = zn;
#pragma unroll
  for (int o = 32; o >= 1; o >>= 1) M = fmaxf(M, __shfl_xor(M, o));
  float sE = (tid < CC) ? __builtin_amdgcn_exp2f(zn - M) : 0.f;
#pragma unroll
  for (int o = 32; o >= 1; o >>= 1) sE += __shfl_xor(sE, o);
  float norm = LN2 * (M + __builtin_amdgcn_logf(sE));

  // --- numerator ---
  const int* lab = labels + b * TT;
  const float* emg = em + (size_t)b * TT * CC;
  float sc = 0.f;
  int msum = 0;
  for (int k = tid; k < TT; k += 64) {
    int mk = mask[b * TT + k];
    msum += mk;
    if (k >= 1) {
      int tg = lab[k], tp = lab[k - 1];
      sc += (tr[tp * CC + tg] + emg[k * CC + tg]) * (float)mk;
    }
  }
#pragma unroll
  for (int o = 32; o >= 1; o >>= 1) {
    sc += __shfl_xor(sc, o);
    msum += __shfl_xor(msum, o);
  }
  int seq_end = msum - 1;
  int t0 = lab[0], tl = lab[seq_end];
  float score = sc + st[t0] + emg[t0] + en[tl];
  // loss = mean(norm - score); out[0] pre-zeroed by packw_kernel
  if (tid == 0) atomicAdd(out, (norm - score) * (1.0f / 64.0f));
}

extern "C" void kernel_launch(void* const* d_in, const int* in_sizes, int n_in,
                              void* d_out, int out_size, void* d_ws, size_t ws_size,
                              hipStream_t stream) {
  const float* hidden = (const float*)d_in[0];
  const int* amask = (const int*)d_in[1];
  const int* labels = (const int*)d_in[2];
  const float* fc_w = (const float*)d_in[3];
  const float* fc_b = (const float*)d_in[4];
  const float* st = (const float*)d_in[5];
  const float* en = (const float*)d_in[6];
  const float* tr = (const float*)d_in[7];

  float* emws = (float*)d_ws;                          // 655360 floats
  float* llh = emws + (size_t)BB * TT * CC;            // 64 (unused, keeps layout)
  short* wfrag = (short*)(llh + 64);                   // 24576 shorts
  float* amw = (float*)(wfrag + 24576);                // 1280
  float* bmw = amw + BB * CC;
  float* avw = bmw + BB * CC;
  float* bvw = avw + BB * CC;
  unsigned char* bpws = (unsigned char*)(bvw + BB * CC);  // 327680 B (16B aligned)
  unsigned char* fpws = bpws + (size_t)BB * MID * CC;     // 327680 B
  float* out = (float*)d_out;

  packw_kernel<<<(2 * 24 * 64) / 256, 256, 0, stream>>>(fc_w, wfrag, out);
  emissions_kernel<<<(BB * TT) / 64, 256, 0, stream>>>(hidden, wfrag, fc_b, emws);
  crf_half_kernel<<<4 * BB, 64, 0, stream>>>(emws, amask, st, en, tr,
                                             amw, bmw, avw, bvw, bpws, fpws);
  finish_kernel<<<BB, 64, 0, stream>>>(emws, amask, labels, st, en, tr,
                                       amw, bmw, avw, bvw, bpws, fpws, out);
}

// Round 7
// 238.312 us; speedup vs baseline: 1.6730x; 1.0220x over previous
//
#include <hip/hip_runtime.h>
#include <hip/hip_bf16.h>

#define BB 64
#define TT 512
#define EE 768
#define CC 20
#define MID 256

typedef __attribute__((ext_vector_type(8))) short bf16x8;
typedef __attribute__((ext_vector_type(4))) float f32x4;

__device__ __forceinline__ float rlane(float x, int l) {
  return __int_as_float(__builtin_amdgcn_readlane(__float_as_int(x), l));
}
__device__ __forceinline__ short f2bf(float x) {
  union { __hip_bfloat16 h; short s; } u;
  u.h = __float2bfloat16(x);
  return u.s;
}
__device__ __forceinline__ bf16x8 pack8(float4 a, float4 b) {
  bf16x8 r;
  r[0] = f2bf(a.x); r[1] = f2bf(a.y); r[2] = f2bf(a.z); r[3] = f2bf(a.w);
  r[4] = f2bf(b.x); r[5] = f2bf(b.y); r[6] = f2bf(b.z); r[7] = f2bf(b.w);
  return r;
}

// ---------------- pre-pack fc_w into B-fragment layout (bf16); zero loss slot
__global__ __launch_bounds__(256) void packw_kernel(const float* __restrict__ fc_w,
                                                    short* __restrict__ wfrag,
                                                    float* __restrict__ outp) {
  if (blockIdx.x == 0 && threadIdx.x == 0) outp[0] = 0.f;  // finish accumulates here
  int t = blockIdx.x * 256 + threadIdx.x;  // 0 .. 2*24*64-1
  int lane = t & 63;
  int kc = (t >> 6) % 24;
  int tile = t / (24 * 64);
  int n = tile * 16 + (lane & 15);
  if (n >= CC) n = CC - 1;
  int k0 = kc * 32 + (lane >> 4) * 8;
  const float* src = fc_w + (size_t)n * EE + k0;
  float4 x = *(const float4*)src;
  float4 y = *(const float4*)(src + 4);
  ((bf16x8*)wfrag)[t] = pack8(x, y);
}

// ---------------- emissions: 4 waves/block, 64 tokens/block, W direct from L2.
__global__ __launch_bounds__(256) void emissions_kernel(
    const float* __restrict__ hidden, const short* __restrict__ wfrag,
    const float* __restrict__ fc_b, float* __restrict__ em) {
  const int wave = threadIdx.x >> 6;
  const int lane = threadIdx.x & 63;
  const int token0 = blockIdx.x * 64 + wave * 16;
  const int m = lane & 15, q = lane >> 4;
  const float* hrow = hidden + (size_t)(token0 + m) * EE + q * 8;
  const bf16x8* wp = (const bf16x8*)wfrag;  // 48 KiB, L2-resident broadcast
  f32x4 acc0 = {0.f, 0.f, 0.f, 0.f}, acc1 = {0.f, 0.f, 0.f, 0.f};
#pragma unroll 4
  for (int kb = 0; kb < 24; ++kb) {
    float4 a0 = *(const float4*)(hrow + kb * 32);
    float4 a1 = *(const float4*)(hrow + kb * 32 + 4);
    bf16x8 Ab = pack8(a0, a1);
    bf16x8 w0 = wp[kb * 64 + lane];
    bf16x8 w1 = wp[(24 + kb) * 64 + lane];
    acc0 = __builtin_amdgcn_mfma_f32_16x16x32_bf16(Ab, w0, acc0, 0, 0, 0);
    acc1 = __builtin_amdgcn_mfma_f32_16x16x32_bf16(Ab, w1, acc1, 0, 0, 0);
  }
  const int col = lane & 15;
  const float b0v = fc_b[col];
  const bool has1 = (16 + col < CC);
  const float b1v = has1 ? fc_b[16 + col] : 0.f;
#pragma unroll
  for (int r = 0; r < 4; ++r) {
    int tok = token0 + q * 4 + r;
    em[(size_t)tok * CC + col] = acc0[r] + b0v;
    if (has1) em[(size_t)tok * CC + 16 + col] = acc1[r] + b1v;
  }
}

// ---- LDS-broadcast step kernels: state vector arrives as 5x float4 broadcast.
__device__ __forceinline__ unsigned umax_(unsigned a, unsigned b) { return a > b ? a : b; }
__device__ __forceinline__ unsigned umax3_(unsigned a, unsigned b, unsigned c) {
  return umax_(umax_(a, b), c);
}
// packed-u32 argmax over 20 biased-positive values (VCC-free).
__device__ __forceinline__ void vstep_lds(float4 x0, float4 x1, float4 x2, float4 x3,
                                          float4 x4, const float (&tv)[CC],
                                          float& vm, int& jm) {
  float v0 = x0.x + tv[0], v1 = x0.y + tv[1], v2 = x0.z + tv[2], v3 = x0.w + tv[3];
  float v4 = x1.x + tv[4], v5 = x1.y + tv[5], v6 = x1.z + tv[6], v7 = x1.w + tv[7];
  float v8 = x2.x + tv[8], v9 = x2.y + tv[9], v10 = x2.z + tv[10], v11 = x2.w + tv[11];
  float v12 = x3.x + tv[12], v13 = x3.y + tv[13], v14 = x3.z + tv[14], v15 = x3.w + tv[15];
  float v16 = x4.x + tv[16], v17 = x4.y + tv[17], v18 = x4.z + tv[18], v19 = x4.w + tv[19];
#define PKEY(Q) unsigned p##Q = (__float_as_uint(v##Q) & 0xFFFFFFE0u) | Q##u;
  PKEY(0) PKEY(1) PKEY(2) PKEY(3) PKEY(4) PKEY(5) PKEY(6) PKEY(7)
  PKEY(8) PKEY(9) PKEY(10) PKEY(11) PKEY(12) PKEY(13) PKEY(14)
  PKEY(15) PKEY(16) PKEY(17) PKEY(18) PKEY(19)
#undef PKEY
  unsigned m0 = umax3_(p0, p1, p2);
  unsigned m1 = umax3_(p3, p4, p5);
  unsigned m2 = umax3_(p6, p7, p8);
  unsigned m3 = umax3_(p9, p10, p11);
  unsigned m4 = umax3_(p12, p13, p14);
  unsigned m5 = umax3_(p15, p16, p17);
  unsigned n0 = umax3_(m0, m1, m2);
  unsigned n1 = umax3_(m3, m4, m5);
  unsigned n2 = umax_(p18, p19);
  unsigned r = umax3_(n0, n1, n2);
  vm = __uint_as_float(r & 0xFFFFFFE0u);
  jm = (int)(r & 31u);
}
// dot(x, ET): same accumulator grouping/order as before -> bitwise identical.
__device__ __forceinline__ float fdot_lds(float4 x0, float4 x1, float4 x2, float4 x3,
                                          float4 x4, const float (&ET)[CC]) {
  float s0 = x0.x * ET[0];
  float s1 = x0.y * ET[1];
  float s2 = x0.z * ET[2];
  float s3 = x0.w * ET[3];
  s0 = fmaf(x1.x, ET[4], s0);
  s1 = fmaf(x1.y, ET[5], s1);
  s2 = fmaf(x1.z, ET[6], s2);
  s3 = fmaf(x1.w, ET[7], s3);
  s0 = fmaf(x2.x, ET[8], s0);
  s1 = fmaf(x2.y, ET[9], s1);
  s2 = fmaf(x2.z, ET[10], s2);
  s3 = fmaf(x2.w, ET[11], s3);
  s0 = fmaf(x3.x, ET[12], s0);
  s1 = fmaf(x3.y, ET[13], s1);
  s2 = fmaf(x3.z, ET[14], s2);
  s3 = fmaf(x3.w, ET[15], s3);
  s0 = fmaf(x4.x, ET[16], s0);
  s1 = fmaf(x4.y, ET[17], s1);
  s2 = fmaf(x4.z, ET[18], s2);
  s3 = fmaf(x4.w, ET[19], s3);
  return (s0 + s1) + (s2 + s3);
}

#define XDECL(Q) float x##Q = rlane(x, Q); int y##Q = Q;
#define MRX(A_, B_) { bool k_ = (x##A_ >= x##B_); x##A_ = k_ ? x##A_ : x##B_; y##A_ = k_ ? y##A_ : y##B_; }
__device__ __forceinline__ int lane_argmax(float x) {
  XDECL(0) XDECL(1) XDECL(2) XDECL(3) XDECL(4) XDECL(5) XDECL(6) XDECL(7)
  XDECL(8) XDECL(9) XDECL(10) XDECL(11) XDECL(12) XDECL(13) XDECL(14)
  XDECL(15) XDECL(16) XDECL(17) XDECL(18) XDECL(19)
  MRX(0, 10) MRX(1, 11) MRX(2, 12) MRX(3, 13) MRX(4, 14)
  MRX(5, 15) MRX(6, 16) MRX(7, 17) MRX(8, 18) MRX(9, 19)
  MRX(0, 5) MRX(1, 6) MRX(2, 7) MRX(3, 8) MRX(4, 9)
  MRX(0, 1) MRX(2, 3)
  MRX(0, 2) MRX(0, 4)
  return y0;
}

// ---------------- CRF halves. quad: 0=fwd-fore 1=fwd-back 2=vit-fore 3=vit-back
// Branch-free hot loops: per-step renorm derived from the broadcast x0.x
// (no readlane, no branch); unconditional clamped stores (no exec-mask);
// state ds_write issued before the bp store.
__global__ __launch_bounds__(64) void crf_half_kernel(
    const float* __restrict__ em, const int* __restrict__ mask,
    const float* __restrict__ st, const float* __restrict__ en,
    const float* __restrict__ tr,
    float* __restrict__ amw, float* __restrict__ bmw,
    float* __restrict__ avw, float* __restrict__ bvw,
    unsigned char* __restrict__ bpws, unsigned char* __restrict__ fpws) {
  __shared__ __align__(16) float emsh[(MID + 1) * CC];  // fore rows 0..256 / back rows 256..511
  __shared__ int msh[TT];
  __shared__ __align__(16) float ssh[64];  // state broadcast buffer (0..19 used)
  const int tid = threadIdx.x;
  const int quad = blockIdx.x >> 6;
  const int b = blockIdx.x & (BB - 1);
  const int back = quad & 1;
  const int cc = tid < CC ? tid : CC - 1;
  const float K = 1.44269504088896340736f;
  const float BIAS = 64.0f;
  const float4* sv = (const float4*)ssh;

  {
    const float* base = em + (size_t)b * TT * CC + (back ? MID * CC : 0);
    int nf4 = back ? (MID * CC / 4) : ((MID + 1) * CC / 4);  // 1280 or 1285
    const float4* src = (const float4*)base;
    float4* dst = (float4*)emsh;
    for (int i = tid; i < nf4; i += 64) dst[i] = src[i];
    for (int i = tid; i < TT; i += 64) msh[i] = mask[b * TT + i];
  }
  __syncthreads();

  if (quad == 0) {
    // ===== forward alpha, t=1..MID, linear domain, per-step pow2 renorm =====
    float ET[CC];
#pragma unroll
    for (int q = 0; q < CC; ++q) ET[q] = __builtin_amdgcn_exp2f(tr[q * CC + cc] * K);
    float r = st[cc] + emsh[cc];
    float base0 = rlane(r, 0);
    float Es = __builtin_amdgcn_exp2f((r - base0) * K);
    float off = base0 * K;
    int ie = 0;
    ssh[tid] = Es;
    float eec = __builtin_amdgcn_exp2f(emsh[CC + cc] * K);
    int mcur = msh[1];
    for (int t = 1; t <= MID; ++t) {
      float4 x0 = sv[0], x1 = sv[1], x2 = sv[2], x3 = sv[3], x4 = sv[4];
      // exact pow2 renorm constant from broadcast state[0] (uniform, no readlane)
      int xb = __float_as_int(x0.x);
      int e = ((xb >> 23) & 255) - 127;
      float scale = __int_as_float((127 - e) << 23);
      int tn = (t < MID) ? t + 1 : t;
      float emn = emsh[tn * CC + cc];
      int mn = msh[tn];
      float s = fdot_lds(x0, x1, x2, x3, x4, ET) * eec;
      float sn = s * scale;
      float Eold = Es * scale;
      Es = mcur ? sn : Eold;
      ie += e;
      ssh[tid] = Es;
      eec = __builtin_amdgcn_exp2f(emn * K);
      mcur = mn;
    }
    if (tid < CC) amw[b * CC + tid] = off + (float)ie + __builtin_amdgcn_logf(Es);
  } else if (quad == 1) {
    // ===== backward beta, t=T-2..MID, linear, mask-reset to en, pow2 renorm =====
    float ETr[CC];
#pragma unroll
    for (int q = 0; q < CC; ++q) ETr[q] = __builtin_amdgcn_exp2f(tr[cc * CC + q] * K);
    const float ENc = __builtin_amdgcn_exp2f(en[cc] * K);
    float Bs = ENc;
    int ie = 0;
    float ee1 = __builtin_amdgcn_exp2f(emsh[(TT - 1 - MID) * CC + cc] * K);  // exp(em_511)
    int m1 = msh[TT - 1];
    ssh[tid] = Bs * ee1;  // G for first iteration
    for (int t = TT - 2; t >= MID; --t) {
      float4 x0 = sv[0], x1 = sv[1], x2 = sv[2], x3 = sv[3], x4 = sv[4];
      int xb = __float_as_int(x0.x);
      int e = ((xb >> 23) & 255) - 127;
      float scale = __int_as_float((127 - e) << 23);
      float emn = emsh[(t - MID) * CC + cc];  // em_t
      int mn = msh[t];
      float s = fdot_lds(x0, x1, x2, x3, x4, ETr);
      float bsn = s * scale;
      Bs = m1 ? bsn : ENc;
      ie = m1 ? (ie + e) : 0;
      float een = __builtin_amdgcn_exp2f(emn * K);
      ssh[tid] = Bs * een;  // G for next iteration
      m1 = mn;
    }
    if (tid < CC) bmw[b * CC + tid] = (float)ie + __builtin_amdgcn_logf(Bs);
  } else if (quad == 2) {
    // ===== viterbi fore, t=1..MID, per-step uniform re-centering =====
    float tv[CC];
#pragma unroll
    for (int q = 0; q < CC; ++q) tv[q] = tr[q * CC + cc];
    float a = st[cc] + emsh[cc] + BIAS;
    ssh[tid] = a;
    float emc = emsh[CC + cc];
    int mcur = msh[1];
    unsigned char* bp = bpws + (size_t)b * MID * CC;
    for (int t = 1; t <= MID; ++t) {
      float4 x0 = sv[0], x1 = sv[1], x2 = sv[2], x3 = sv[3], x4 = sv[4];
      float shift = BIAS - x0.x;  // uniform: argmax/backpointer-invariant
      int tn = (t < MID) ? t + 1 : t;
      float emn = emsh[tn * CC + cc];
      int mn = msh[tn];
      float vm;
      int jm;
      vstep_lds(x0, x1, x2, x3, x4, tv, vm, jm);
      float adc = emc + shift;   // off critical path (parallel with tree)
      float aold = a + shift;
      float au = vm + adc;
      a = mcur ? au : aold;
      ssh[tid] = a;              // recurrence write first
      bp[(t - 1) * CC + cc] = (unsigned char)jm;  // clamped col: lanes>=20 dup lane19
      emc = emn;
      mcur = mn;
    }
    if (tid < CC) avw[b * CC + tid] = a;
  } else {
    // ===== viterbi back, t=T-2..MID, per-step uniform re-centering =====
    float tv[CC];
#pragma unroll
    for (int q = 0; q < CC; ++q) tv[q] = tr[cc * CC + q];  // row of tr
    const float ENv = en[cc] + BIAS;
    float Vb = ENv;
    float em1 = emsh[(TT - 1 - MID) * CC + cc];
    int m1 = msh[TT - 1];
    ssh[tid] = Vb + em1;  // av for first iteration
    unsigned char* fp = fpws + (size_t)b * MID * CC;
    for (int t = TT - 2; t >= MID; --t) {
      float4 x0 = sv[0], x1 = sv[1], x2 = sv[2], x3 = sv[3], x4 = sv[4];
      float shift = BIAS - x0.x;
      float emn = emsh[(t - MID) * CC + cc];
      int mn = msh[t];
      float vm;
      int jm;
      vstep_lds(x0, x1, x2, x3, x4, tv, vm, jm);
      float vs = vm + shift;
      Vb = m1 ? vs : ENv;        // masked: exact reset to ENv
      ssh[tid] = Vb + emn;       // av for next iteration (write first)
      fp[(t - MID) * CC + cc] = (unsigned char)jm;
      em1 = emn;
      m1 = mn;
    }
    if (tid < CC) bvw[b * CC + tid] = Vb;
  }
}

// ---------------- finish: join halves, backtrace both ways, numerator, llh, loss
__global__ __launch_bounds__(64) void finish_kernel(
    const float* __restrict__ em, const int* __restrict__ mask,
    const int* __restrict__ labels, const float* __restrict__ st,
    const float* __restrict__ en, const float* __restrict__ tr,
    const float* __restrict__ amw, const float* __restrict__ bmw,
    const float* __restrict__ avw, const float* __restrict__ bvw,
    const unsigned char* __restrict__ bpws, const unsigned char* __restrict__ fpws,
    float* __restrict__ out) {
  __shared__ unsigned char hl[2 * MID * CC];  // 10240
  const int b = blockIdx.x;
  const int tid = threadIdx.x;
  const int cc = tid < CC ? tid : CC - 1;
  const float LN2 = 0.69314718055994530942f;
  {
    const int4* bsrc = (const int4*)(bpws + (size_t)b * MID * CC);
    const int4* fsrc = (const int4*)(fpws + (size_t)b * MID * CC);
    int4* dst = (int4*)hl;
    for (int i = tid; i < 320; i += 64) {
      dst[i] = bsrc[i];
      dst[320 + i] = fsrc[i];
    }
  }
  __syncthreads();

  // --- viterbi join + dual backtrace ---
  int cstar = lane_argmax(avw[b * CC + cc] + bvw[b * CC + cc]);
  float* ob = out + 1 + (size_t)b * TT;
  if (tid == 0) ob[MID] = (float)(cstar + 1);
  // backward: s = 255..0, tag_s = bp[s][tag_{s+1}] ; 256 = 32*8 exact
  {
    int tag = cstar;
    int s = MID - 1;
    while (s >= 7) {
      int g0 = hl[(s - 0) * CC + cc];
      int g1 = hl[(s - 1) * CC + cc];
      int g2 = hl[(s - 2) * CC + cc];
      int g3 = hl[(s - 3) * CC + cc];
      int g4 = hl[(s - 4) * CC + cc];
      int g5 = hl[(s - 5) * CC + cc];
      int g6 = hl[(s - 6) * CC + cc];
      int g7 = hl[(s - 7) * CC + cc];
      tag = __builtin_amdgcn_readlane(g0, tag); float f0 = (float)(tag + 1);
      tag = __builtin_amdgcn_readlane(g1, tag); float f1 = (float)(tag + 1);
      tag = __builtin_amdgcn_readlane(g2, tag); float f2 = (float)(tag + 1);
      tag = __builtin_amdgcn_readlane(g3, tag); float f3 = (float)(tag + 1);
      tag = __builtin_amdgcn_readlane(g4, tag); float f4 = (float)(tag + 1);
      tag = __builtin_amdgcn_readlane(g5, tag); float f5 = (float)(tag + 1);
      tag = __builtin_amdgcn_readlane(g6, tag); float f6 = (float)(tag + 1);
      tag = __builtin_amdgcn_readlane(g7, tag); float f7 = (float)(tag + 1);
      if (tid == 0) {
        ob[s - 0] = f0; ob[s - 1] = f1; ob[s - 2] = f2; ob[s - 3] = f3;
        ob[s - 4] = f4; ob[s - 5] = f5; ob[s - 6] = f6; ob[s - 7] = f7;
      }
      s -= 8;
    }
  }
  // forward: u = 0..254, tag_{t+1} = fp[u][tag_t], t = MID+u
  {
    int tag = cstar;
    int u = 0;
    while (u + 7 <= MID - 2) {
      int g0 = hl[MID * CC + (u + 0) * CC + cc];
      int g1 = hl[MID * CC + (u + 1) * CC + cc];
      int g2 = hl[MID * CC + (u + 2) * CC + cc];
      int g3 = hl[MID * CC + (u + 3) * CC + cc];
      int g4 = hl[MID * CC + (u + 4) * CC + cc];
      int g5 = hl[MID * CC + (u + 5) * CC + cc];
      int g6 = hl[MID * CC + (u + 6) * CC + cc];
      int g7 = hl[MID * CC + (u + 7) * CC + cc];
      tag = __builtin_amdgcn_readlane(g0, tag); float f0 = (float)(tag + 1);
      tag = __builtin_amdgcn_readlane(g1, tag); float f1 = (float)(tag + 1);
      tag = __builtin_amdgcn_readlane(g2, tag); float f2 = (float)(tag + 1);
      tag = __builtin_amdgcn_readlane(g3, tag); float f3 = (float)(tag + 1);
      tag = __builtin_amdgcn_readlane(g4, tag); float f4 = (float)(tag + 1);
      tag = __builtin_amdgcn_readlane(g5, tag); float f5 = (float)(tag + 1);
      tag = __builtin_amdgcn_readlane(g6, tag); float f6 = (float)(tag + 1);
      tag = __builtin_amdgcn_readlane(g7, tag); float f7 = (float)(tag + 1);
      if (tid == 0) {
        ob[MID + 1 + u + 0] = f0; ob[MID + 1 + u + 1] = f1;
        ob[MID + 1 + u + 2] = f2; ob[MID + 1 + u + 3] = f3;
        ob[MID + 1 + u + 4] = f4; ob[MID + 1 + u + 5] = f5;
        ob[MID + 1 + u + 6] = f6; ob[MID + 1 + u + 7] = f7;
      }
      u += 8;
    }
    while (u <= MID - 2) {
      int g = hl[MID * CC + u * CC + cc];
      tag = __builtin_amdgcn_readlane(g, tag);
      if (tid == 0) ob[MID + 1 + u] = (float)(tag + 1);
      ++u;
    }
  }

  // --- norm = LN2 * lse2(am + bm) ---
  float zn = amw[b * CC + cc] + bmw[b * CC + cc];
  float M = zn;
#pragma unroll
  for (int o = 32; o >= 1; o >>= 1) M = fmaxf(M, __shfl_xor(M, o));
  float sE = (tid < CC) ? __builtin_amdgcn_exp2f(zn - M) : 0.f;
#pragma unroll
  for (int o = 32; o >= 1; o >>= 1) sE += __shfl_xor(sE, o);
  float norm = LN2 * (M + __builtin_amdgcn_logf(sE));

  // --- numerator ---
  const int* lab = labels + b * TT;
  const float* emg = em + (size_t)b * TT * CC;
  float sc = 0.f;
  int msum = 0;
  for (int k = tid; k < TT; k += 64) {
    int mk = mask[b * TT + k];
    msum += mk;
    if (k >= 1) {
      int tg = lab[k], tp = lab[k - 1];
      sc += (tr[tp * CC + tg] + emg[k * CC + tg]) * (float)mk;
    }
  }
#pragma unroll
  for (int o = 32; o >= 1; o >>= 1) {
    sc += __shfl_xor(sc, o);
    msum += __shfl_xor(msum, o);
  }
  int seq_end = msum - 1;
  int t0 = lab[0], tl = lab[seq_end];
  float score = sc + st[t0] + emg[t0] + en[tl];
  // loss = mean(norm - score); out[0] pre-zeroed by packw_kernel
  if (tid == 0) atomicAdd(out, (norm - score) * (1.0f / 64.0f));
}

extern "C" void kernel_launch(void* const* d_in, const int* in_sizes, int n_in,
                              void* d_out, int out_size, void* d_ws, size_t ws_size,
                              hipStream_t stream) {
  const float* hidden = (const float*)d_in[0];
  const int* amask = (const int*)d_in[1];
  const int* labels = (const int*)d_in[2];
  const float* fc_w = (const float*)d_in[3];
  const float* fc_b = (const float*)d_in[4];
  const float* st = (const float*)d_in[5];
  const float* en = (const float*)d_in[6];
  const float* tr = (const float*)d_in[7];

  float* emws = (float*)d_ws;                          // 655360 floats
  float* llh = emws + (size_t)BB * TT * CC;            // 64 (unused, keeps layout)
  short* wfrag = (short*)(llh + 64);                   // 24576 shorts
  float* amw = (float*)(wfrag + 24576);                // 1280
  float* bmw = amw + BB * CC;
  float* avw = bmw + BB * CC;
  float* bvw = avw + BB * CC;
  unsigned char* bpws = (unsigned char*)(bvw + BB * CC);  // 327680 B (16B aligned)
  unsigned char* fpws = bpws + (size_t)BB * MID * CC;     // 327680 B
  float* out = (float*)d_out;

  packw_kernel<<<(2 * 24 * 64) / 256, 256, 0, stream>>>(fc_w, wfrag, out);
  emissions_kernel<<<(BB * TT) / 64, 256, 0, stream>>>(hidden, wfrag, fc_b, emws);
  crf_half_kernel<<<4 * BB, 64, 0, stream>>>(emws, amask, st, en, tr,
                                             amw, bmw, avw, bvw, bpws, fpws);
  finish_kernel<<<BB, 64, 0, stream>>>(emws, amask, labels, st, en, tr,
                                       amw, bmw, avw, bvw, bpws, fpws, out);
}